// Round 1
// baseline (5445.699 us; speedup 1.0000x reference)
//
#include <hip/hip_runtime.h>
#include <math.h>

#define NRAY 8192
#define SSAMP 128
#define HD 256
#define MPTS 32    // points per block in coarse/secant kernels
#define MPTSF 16   // points per block in final dual kernel

__device__ __forceinline__ float softplusf(float x) {
    return fmaxf(x, 0.0f) + log1pf(expf(-fabsf(x)));
}
__device__ __forceinline__ float sigmoidf_(float x) {
    return 1.0f / (1.0f + expf(-x));
}
__device__ __forceinline__ void fma4(float4& a, float s, const float4 w) {
    a.x = fmaf(s, w.x, a.x); a.y = fmaf(s, w.y, a.y);
    a.z = fmaf(s, w.z, a.z); a.w = fmaf(s, w.w, a.w);
}

// ---------------- MLP layer helpers (activations live in LDS) ----------------
// Layout: act[m*HD + i], m = point index within block. Reads are wave-broadcast
// (all lanes same address -> conflict-free); writes are contiguous b128.

// layer1: 3 -> 256.  pts[m*4 + c]
template<int MPW>
__device__ __forceinline__ void mlp_layer1(const float* __restrict__ W1, const float* __restrict__ b1,
                                           const float* pts, float* out_lds, int tid) {
    const int lane = tid & 63, wave = tid >> 6;
    const int j0 = lane << 2, mg = wave * MPW;
    float4 w0 = *(const float4*)(W1 + 0 * HD + j0);
    float4 w1 = *(const float4*)(W1 + 1 * HD + j0);
    float4 w2 = *(const float4*)(W1 + 2 * HD + j0);
    float4 bb = *(const float4*)(b1 + j0);
#pragma unroll
    for (int mi = 0; mi < MPW; mi++) {
        int m = mg + mi;
        float px = pts[m * 4 + 0], py = pts[m * 4 + 1], pz = pts[m * 4 + 2];
        float4 z = bb;
        fma4(z, px, w0); fma4(z, py, w1); fma4(z, pz, w2);
        float4 o;
        o.x = softplusf(z.x); o.y = softplusf(z.y); o.z = softplusf(z.z); o.w = softplusf(z.w);
        *(float4*)(out_lds + m * HD + j0) = o;
    }
}

// layer1 with tangent: value p, tangent t (= rd). h_t = sigmoid(z) * (t @ W1)
template<int MPW>
__device__ __forceinline__ void mlp_layer1_dual(const float* __restrict__ W1, const float* __restrict__ b1,
                                                const float* pv, const float* pt,
                                                float* outv, float* outt, int tid) {
    const int lane = tid & 63, wave = tid >> 6;
    const int j0 = lane << 2, mg = wave * MPW;
    float4 w0 = *(const float4*)(W1 + 0 * HD + j0);
    float4 w1 = *(const float4*)(W1 + 1 * HD + j0);
    float4 w2 = *(const float4*)(W1 + 2 * HD + j0);
    float4 bb = *(const float4*)(b1 + j0);
#pragma unroll
    for (int mi = 0; mi < MPW; mi++) {
        int m = mg + mi;
        float px = pv[m * 4 + 0], py = pv[m * 4 + 1], pz = pv[m * 4 + 2];
        float tx = pt[m * 4 + 0], ty = pt[m * 4 + 1], tz = pt[m * 4 + 2];
        float4 z = bb;
        fma4(z, px, w0); fma4(z, py, w1); fma4(z, pz, w2);
        float4 zt = make_float4(0.f, 0.f, 0.f, 0.f);
        fma4(zt, tx, w0); fma4(zt, ty, w1); fma4(zt, tz, w2);
        float4 o, ot;
        o.x = softplusf(z.x); o.y = softplusf(z.y); o.z = softplusf(z.z); o.w = softplusf(z.w);
        ot.x = sigmoidf_(z.x) * zt.x; ot.y = sigmoidf_(z.y) * zt.y;
        ot.z = sigmoidf_(z.z) * zt.z; ot.w = sigmoidf_(z.w) * zt.w;
        *(float4*)(outv + m * HD + j0) = o;
        *(float4*)(outt + m * HD + j0) = ot;
    }
}

// 256 -> 256 layer. Each lane owns 4 output cols (j0..j0+3) for MPW points.
template<int MPW>
__device__ __forceinline__ void mlp_layer(const float* __restrict__ W, const float* __restrict__ b,
                                          const float* in_lds, float* out_lds, int tid) {
    const int lane = tid & 63, wave = tid >> 6;
    const int j0 = lane << 2, mg = wave * MPW;
    float4 acc[MPW];
#pragma unroll
    for (int mi = 0; mi < MPW; mi++) acc[mi] = make_float4(0.f, 0.f, 0.f, 0.f);
    for (int ii = 0; ii < HD; ii += 4) {
        float4 w0 = *(const float4*)(W + (ii + 0) * HD + j0);
        float4 w1 = *(const float4*)(W + (ii + 1) * HD + j0);
        float4 w2 = *(const float4*)(W + (ii + 2) * HD + j0);
        float4 w3 = *(const float4*)(W + (ii + 3) * HD + j0);
#pragma unroll
        for (int mi = 0; mi < MPW; mi++) {
            float4 h = *(const float4*)(in_lds + (mg + mi) * HD + ii);
            fma4(acc[mi], h.x, w0); fma4(acc[mi], h.y, w1);
            fma4(acc[mi], h.z, w2); fma4(acc[mi], h.w, w3);
        }
    }
    float4 bb = *(const float4*)(b + j0);
#pragma unroll
    for (int mi = 0; mi < MPW; mi++) {
        float4 z = acc[mi];
        z.x += bb.x; z.y += bb.y; z.z += bb.z; z.w += bb.w;
        float4 o;
        o.x = softplusf(z.x); o.y = softplusf(z.y); o.z = softplusf(z.z); o.w = softplusf(z.w);
        *(float4*)(out_lds + (mg + mi) * HD + j0) = o;
    }
}

template<int MPW>
__device__ __forceinline__ void mlp_layer_dual(const float* __restrict__ W, const float* __restrict__ b,
                                               const float* inv, const float* int_,
                                               float* outv, float* outt, int tid) {
    const int lane = tid & 63, wave = tid >> 6;
    const int j0 = lane << 2, mg = wave * MPW;
    float4 accv[MPW], acct[MPW];
#pragma unroll
    for (int mi = 0; mi < MPW; mi++) {
        accv[mi] = make_float4(0.f, 0.f, 0.f, 0.f);
        acct[mi] = make_float4(0.f, 0.f, 0.f, 0.f);
    }
    for (int ii = 0; ii < HD; ii += 4) {
        float4 w0 = *(const float4*)(W + (ii + 0) * HD + j0);
        float4 w1 = *(const float4*)(W + (ii + 1) * HD + j0);
        float4 w2 = *(const float4*)(W + (ii + 2) * HD + j0);
        float4 w3 = *(const float4*)(W + (ii + 3) * HD + j0);
#pragma unroll
        for (int mi = 0; mi < MPW; mi++) {
            float4 hv = *(const float4*)(inv + (mg + mi) * HD + ii);
            float4 ht = *(const float4*)(int_ + (mg + mi) * HD + ii);
            fma4(accv[mi], hv.x, w0); fma4(accv[mi], hv.y, w1);
            fma4(accv[mi], hv.z, w2); fma4(accv[mi], hv.w, w3);
            fma4(acct[mi], ht.x, w0); fma4(acct[mi], ht.y, w1);
            fma4(acct[mi], ht.z, w2); fma4(acct[mi], ht.w, w3);
        }
    }
    float4 bb = *(const float4*)(b + j0);
#pragma unroll
    for (int mi = 0; mi < MPW; mi++) {
        float4 z = accv[mi];
        z.x += bb.x; z.y += bb.y; z.z += bb.z; z.w += bb.w;
        float4 o, ot;
        o.x = softplusf(z.x); o.y = softplusf(z.y); o.z = softplusf(z.z); o.w = softplusf(z.w);
        ot.x = sigmoidf_(z.x) * acct[mi].x; ot.y = sigmoidf_(z.y) * acct[mi].y;
        ot.z = sigmoidf_(z.z) * acct[mi].z; ot.w = sigmoidf_(z.w) * acct[mi].w;
        *(float4*)(outv + (mg + mi) * HD + j0) = o;
        *(float4*)(outt + (mg + mi) * HD + j0) = ot;
    }
}

// ---------------- coarse pass: 4 blocks per ray, 32 samples each ----------------
__global__ __launch_bounds__(256, 2)
void coarse_kernel(const float* __restrict__ ray0, const float* __restrict__ rdg,
                   const float* __restrict__ W1, const float* __restrict__ b1,
                   const float* __restrict__ W2, const float* __restrict__ b2,
                   const float* __restrict__ W3, const float* __restrict__ b3,
                   const float* __restrict__ W4, const float* __restrict__ b4,
                   float* __restrict__ val_out, float* __restrict__ dprop_out) {
    __shared__ __align__(16) float bufA[MPTS * HD];
    __shared__ __align__(16) float bufB[MPTS * HD];
    float* pts = bufB;            // aliased: consumed by layer1 before bufB is written
    float* shp = bufB + MPTS * 4; // 9 floats: dn, dfar, maskc, o0..2, v0..2

    const int tid = threadIdx.x;
    const int blk = blockIdx.x;
    const int r = blk >> 2;
    const int q = blk & 3;

    if (tid == 0) {
        float o0 = ray0[3 * r], o1 = ray0[3 * r + 1], o2 = ray0[3 * r + 2];
        float v0 = rdg[3 * r], v1 = rdg[3 * r + 1], v2 = rdg[3 * r + 2];
        const float pd = 0.55f;       // 0.5 + PADDING/2
        const float lim = pd + 1e-6f; // EPS
        float di[6]; int insk[6]; int cnt = 0;
        for (int k = 0; k < 6; k++) {
            int a = k % 3;
            float pl = (k < 3) ? pd : -pd;
            float den = (a == 0) ? v0 : ((a == 1) ? v1 : v2);
            if (fabsf(den) < 1e-9f) den = 1e-9f;
            float oa = (a == 0) ? o0 : ((a == 1) ? o1 : o2);
            float dd = (pl - oa) / den;
            float px = o0 + dd * v0, py = o1 + dd * v1, pz = o2 + dd * v2;
            int ins = (fabsf(px) <= lim) && (fabsf(py) <= lim) && (fabsf(pz) <= lim);
            di[k] = dd; insk[k] = ins; cnt += ins;
        }
        float dn = 0.f, dfar = 0.f, maskc = 0.f;
        if (cnt == 2) {
            maskc = 1.f;
            int k1 = -1, k2 = -1;
            for (int k = 0; k < 6; k++) if (insk[k]) { if (k1 < 0) k1 = k; else k2 = k; }
            float nrd = sqrtf(v0 * v0 + v1 * v1 + v2 * v2);
            float ax = (o0 + di[k1] * v0) - o0, ay = (o1 + di[k1] * v1) - o1, az = (o2 + di[k1] * v2) - o2;
            float d1n = sqrtf(ax * ax + ay * ay + az * az) / nrd;
            float bx = (o0 + di[k2] * v0) - o0, by = (o1 + di[k2] * v1) - o1, bz = (o2 + di[k2] * v2) - o2;
            float d2n = sqrtf(bx * bx + by * by + bz * bz) / nrd;
            dn = fminf(d1n, d2n); dfar = fmaxf(d1n, d2n);
        }
        shp[0] = dn; shp[1] = dfar; shp[2] = maskc;
        shp[3] = o0; shp[4] = o1; shp[5] = o2;
        shp[6] = v0; shp[7] = v1; shp[8] = v2;
    }
    __syncthreads();
    if (tid < MPTS) {
        int s = q * MPTS + tid;
        float t = (float)s * (1.0f / 127.0f);
        float d = (shp[2] != 0.f) ? (shp[0] + t * (shp[1] - shp[0])) : (t * 2.4f);
        dprop_out[s * NRAY + r] = d;
        pts[tid * 4 + 0] = shp[3] + d * shp[6];
        pts[tid * 4 + 1] = shp[4] + d * shp[7];
        pts[tid * 4 + 2] = shp[5] + d * shp[8];
    }
    __syncthreads();
    mlp_layer1<8>(W1, b1, pts, bufA, tid);
    __syncthreads();
    mlp_layer<8>(W2, b2, bufA, bufB, tid);
    __syncthreads();
    mlp_layer<8>(W3, b3, bufB, bufA, tid);
    __syncthreads();
    // layer4: per-wave shuffle-reduced dot products
    {
        const int lane = tid & 63, wave = tid >> 6;
        const int mg = wave * 8;
        float4 w4 = *(const float4*)(W4 + lane * 4);
        float b4v = b4[0];
#pragma unroll
        for (int mi = 0; mi < 8; mi++) {
            float4 h = *(const float4*)(bufA + (mg + mi) * HD + lane * 4);
            float v = fmaf(h.x, w4.x, fmaf(h.y, w4.y, fmaf(h.z, w4.z, h.w * w4.w)));
            for (int off = 32; off > 0; off >>= 1) v += __shfl_down(v, off, 64);
            if (lane == 0) {
                int s = q * MPTS + mg + mi;
                val_out[s * NRAY + r] = v + b4v;   // LOGIT_TAU = log(1) = 0
            }
        }
    }
}

// ---------------- per-ray sign scan -> bracket + first secant ----------------
__global__ void scan_kernel(const float* __restrict__ val, const float* __restrict__ dprop,
                            float* __restrict__ dlow, float* __restrict__ flow,
                            float* __restrict__ dhigh, float* __restrict__ fhigh,
                            float* __restrict__ dpred, int* __restrict__ maskp) {
    int r = blockIdx.x * blockDim.x + threadIdx.x;
    if (r >= NRAY) return;
    float prev = val[r];
    int mask0 = prev < 0.f;
    float best = 3.4e38f; int bidx = 0;
    for (int s = 0; s < SSAMP - 1; s++) {
        float cur = val[(s + 1) * NRAY + r];
        float pr = prev * cur;
        float sg = (pr > 0.f) ? 1.f : ((pr < 0.f) ? -1.f : 0.f);
        float cost = sg * (float)(SSAMP - s);
        if (cost < best) { best = cost; bidx = s; }
        prev = cur;
    }
    if (1.0f < best) { best = 1.0f; bidx = SSAMP - 1; }  // cost[127] = 1
    float f_low = val[bidx * NRAY + r];
    int idxh = min(bidx + 1, SSAMP - 1);
    float d_low = dprop[bidx * NRAY + r];
    float d_high = dprop[idxh * NRAY + r];
    float f_high = val[idxh * NRAY + r];
    int mk = (best < 0.f) && (f_low < 0.f) && mask0;
    float den = f_high - f_low;
    if (fabsf(den) < 1e-12f) den = 1e-12f;
    float dp = -f_low * (d_high - d_low) / den + d_low;
    dlow[r] = d_low; flow[r] = f_low; dhigh[r] = d_high; fhigh[r] = f_high;
    dpred[r] = dp; maskp[r] = mk;
}

// ---------------- one secant iteration (eval f(d_pred) + bracket update) ----------------
__global__ __launch_bounds__(256, 2)
void secant_kernel(const float* __restrict__ ray0, const float* __restrict__ rdg,
                   const float* __restrict__ W1, const float* __restrict__ b1,
                   const float* __restrict__ W2, const float* __restrict__ b2,
                   const float* __restrict__ W3, const float* __restrict__ b3,
                   const float* __restrict__ W4, const float* __restrict__ b4,
                   float* __restrict__ dlow, float* __restrict__ flow,
                   float* __restrict__ dhigh, float* __restrict__ fhigh,
                   float* __restrict__ dpred) {
    __shared__ __align__(16) float bufA[MPTS * HD];
    __shared__ __align__(16) float bufB[MPTS * HD];
    float* pts = bufB;
    const int tid = threadIdx.x;
    const int rbase = blockIdx.x * MPTS;
    if (tid < MPTS) {
        int r = rbase + tid;
        float dp = dpred[r];
        pts[tid * 4 + 0] = ray0[3 * r + 0] + dp * rdg[3 * r + 0];
        pts[tid * 4 + 1] = ray0[3 * r + 1] + dp * rdg[3 * r + 1];
        pts[tid * 4 + 2] = ray0[3 * r + 2] + dp * rdg[3 * r + 2];
    }
    __syncthreads();
    mlp_layer1<8>(W1, b1, pts, bufA, tid);
    __syncthreads();
    mlp_layer<8>(W2, b2, bufA, bufB, tid);
    __syncthreads();
    mlp_layer<8>(W3, b3, bufB, bufA, tid);
    __syncthreads();
    {
        const int lane = tid & 63, wave = tid >> 6;
        const int mg = wave * 8;
        float4 w4 = *(const float4*)(W4 + lane * 4);
        float b4v = b4[0];
#pragma unroll
        for (int mi = 0; mi < 8; mi++) {
            float4 h = *(const float4*)(bufA + (mg + mi) * HD + lane * 4);
            float v = fmaf(h.x, w4.x, fmaf(h.y, w4.y, fmaf(h.z, w4.z, h.w * w4.w)));
            for (int off = 32; off > 0; off >>= 1) v += __shfl_down(v, off, 64);
            if (lane == 0) {
                int r = rbase + mg + mi;
                float fm = v + b4v;
                float dp = dpred[r];
                float dl = dlow[r], fl = flow[r], dh = dhigh[r], fh = fhigh[r];
                if (fm < 0.f) { dl = dp; fl = fm; } else { dh = dp; fh = fm; }
                float den = fh - fl;
                if (fabsf(den) < 1e-12f) den = 1e-12f;
                dp = -fl * (dh - dl) / den + dl;
                dlow[r] = dl; flow[r] = fl; dhigh[r] = dh; fhigh[r] = fh; dpred[r] = dp;
            }
        }
    }
}

// ---------------- final: dual-number (JVP) eval + implicit correction ----------------
__global__ void final_kernel(const float* __restrict__ ray0, const float* __restrict__ rdg,
                             const float* __restrict__ W1, const float* __restrict__ b1,
                             const float* __restrict__ W2, const float* __restrict__ b2,
                             const float* __restrict__ W3, const float* __restrict__ b3,
                             const float* __restrict__ W4, const float* __restrict__ b4,
                             const float* __restrict__ dpred, const int* __restrict__ maskp,
                             float* __restrict__ out) {
    __shared__ __align__(16) float Av[MPTSF * HD];
    __shared__ __align__(16) float At[MPTSF * HD];
    __shared__ __align__(16) float Bv[MPTSF * HD];
    __shared__ __align__(16) float Bt[MPTSF * HD];
    float* pv = Bv;
    float* pt = Bv + MPTSF * 4;
    const int tid = threadIdx.x;
    const int rbase = blockIdx.x * MPTSF;
    if (tid < MPTSF) {
        int r = rbase + tid;
        float ds = dpred[r];
        float v0 = rdg[3 * r + 0], v1 = rdg[3 * r + 1], v2 = rdg[3 * r + 2];
        pv[tid * 4 + 0] = ray0[3 * r + 0] + ds * v0;
        pv[tid * 4 + 1] = ray0[3 * r + 1] + ds * v1;
        pv[tid * 4 + 2] = ray0[3 * r + 2] + ds * v2;
        pt[tid * 4 + 0] = v0; pt[tid * 4 + 1] = v1; pt[tid * 4 + 2] = v2;
    }
    __syncthreads();
    mlp_layer1_dual<4>(W1, b1, pv, pt, Av, At, tid);
    __syncthreads();
    mlp_layer_dual<4>(W2, b2, Av, At, Bv, Bt, tid);
    __syncthreads();
    mlp_layer_dual<4>(W3, b3, Bv, Bt, Av, At, tid);
    __syncthreads();
    {
        const int lane = tid & 63, wave = tid >> 6;
        const int mg = wave * 4;
        float4 w4 = *(const float4*)(W4 + lane * 4);
        float b4v = b4[0];
#pragma unroll
        for (int mi = 0; mi < 4; mi++) {
            float4 hv = *(const float4*)(Av + (mg + mi) * HD + lane * 4);
            float4 ht = *(const float4*)(At + (mg + mi) * HD + lane * 4);
            float fv = fmaf(hv.x, w4.x, fmaf(hv.y, w4.y, fmaf(hv.z, w4.z, hv.w * w4.w)));
            float ft = fmaf(ht.x, w4.x, fmaf(ht.y, w4.y, fmaf(ht.z, w4.z, ht.w * w4.w)));
            for (int off = 32; off > 0; off >>= 1) {
                fv += __shfl_down(fv, off, 64);
                ft += __shfl_down(ft, off, 64);
            }
            if (lane == 0) {
                int r = rbase + mg + mi;
                float f = fv + b4v;       // - LOGIT_TAU (= 0)
                float dfdd = ft;
                if (fabsf(dfdd) < 1e-6f) dfdd = (dfdd < 0.f) ? -1e-6f : 1e-6f;
                float dres = dpred[r] - f / dfdd;
                out[r] = maskp[r] ? dres : 0.0f;
            }
        }
    }
}

extern "C" void kernel_launch(void* const* d_in, const int* in_sizes, int n_in,
                              void* d_out, int out_size, void* d_ws, size_t ws_size,
                              hipStream_t stream) {
    const float* ray0 = (const float*)d_in[0];
    const float* rdg  = (const float*)d_in[1];
    const float* W1 = (const float*)d_in[2];
    const float* b1 = (const float*)d_in[3];
    const float* W2 = (const float*)d_in[4];
    const float* b2 = (const float*)d_in[5];
    const float* W3 = (const float*)d_in[6];
    const float* b3 = (const float*)d_in[7];
    const float* W4 = (const float*)d_in[8];
    const float* b4 = (const float*)d_in[9];
    float* out = (float*)d_out;

    float* ws = (float*)d_ws;
    float* val    = ws;                                // SSAMP*NRAY, s-major
    float* dprop  = ws + (size_t)SSAMP * NRAY;         // SSAMP*NRAY, s-major
    float* s_dlow  = ws + (size_t)2 * SSAMP * NRAY;
    float* s_flow  = s_dlow + NRAY;
    float* s_dhigh = s_flow + NRAY;
    float* s_fhigh = s_dhigh + NRAY;
    float* s_dpred = s_fhigh + NRAY;
    int*   s_mask  = (int*)(s_dpred + NRAY);

    hipLaunchKernelGGL(coarse_kernel, dim3(NRAY * 4), dim3(256), 0, stream,
                       ray0, rdg, W1, b1, W2, b2, W3, b3, W4, b4, val, dprop);
    hipLaunchKernelGGL(scan_kernel, dim3(NRAY / 256), dim3(256), 0, stream,
                       val, dprop, s_dlow, s_flow, s_dhigh, s_fhigh, s_dpred, s_mask);
    for (int it = 0; it < 8; it++) {
        hipLaunchKernelGGL(secant_kernel, dim3(NRAY / MPTS), dim3(256), 0, stream,
                           ray0, rdg, W1, b1, W2, b2, W3, b3, W4, b4,
                           s_dlow, s_flow, s_dhigh, s_fhigh, s_dpred);
    }
    hipLaunchKernelGGL(final_kernel, dim3(NRAY / MPTSF), dim3(256), 0, stream,
                       ray0, rdg, W1, b1, W2, b2, W3, b3, W4, b4,
                       s_dpred, s_mask, out);
}

// Round 2
// 1902.689 us; speedup vs baseline: 2.8621x; 2.8621x over previous
//
#include <hip/hip_runtime.h>
#include <math.h>

#define NRAY 8192
#define SSAMP 128
#define HD 256
#define AROW 264   // padded LDS row pitch in bf16 elems (264*2B = 528B, 16B-aligned)

typedef short s16x8 __attribute__((ext_vector_type(8)));
typedef float f32x4 __attribute__((ext_vector_type(4)));

// ---------- bf16 helpers (RNE) ----------
__device__ __forceinline__ unsigned short f2bf(float f) {
    unsigned u = __float_as_uint(f);
    u += 0x7fffu + ((u >> 16) & 1u);
    return (unsigned short)(u >> 16);
}
__device__ __forceinline__ float bf2f(unsigned short s) {
    return __uint_as_float(((unsigned)s) << 16);
}
__device__ __forceinline__ float softplus_fast(float x) {
    return fmaxf(x, 0.0f) + __logf(1.0f + __expf(-fabsf(x)));
}
__device__ __forceinline__ float softplus_precise(float x) {
    return fmaxf(x, 0.0f) + log1pf(expf(-fabsf(x)));
}
__device__ __forceinline__ float sigmoid_fast(float x) {
    return 1.0f / (1.0f + __expf(-x));
}

// ---------- weight pack: fp32 W[k][n] -> split bf16 B-fragments ----------
// B-frag (16x16x32): lane holds B[k = (lane>>4)*8 + j][n = lane&15], j=0..7 contiguous.
// frag id = ((nt*8 + kt)*2 + hl); each frag = 512 bf16 = lane*8 + j.
__global__ void pack_kernel(const float* __restrict__ W2, const float* __restrict__ W3,
                            unsigned short* __restrict__ P2, unsigned short* __restrict__ P3) {
    int idx = blockIdx.x * 256 + threadIdx.x;   // 0..65535
    int k = idx >> 8, n = idx & 255;
    int nt = n >> 4, kt = k >> 5, lq = (k >> 3) & 3, j = k & 7;
    int lane = (lq << 4) | (n & 15);
    size_t off = (size_t)((nt * 8 + kt) * 2) * 512 + (size_t)lane * 8 + j;
    float w = W2[idx];
    unsigned short hi = f2bf(w);
    P2[off] = hi; P2[off + 512] = f2bf(w - bf2f(hi));
    w = W3[idx];
    hi = f2bf(w);
    P3[off] = hi; P3[off + 512] = f2bf(w - bf2f(hi));
}

// ---------- 4-term split GEMM: acc[MT][4] += (Ahi+Alo) @ (Bhi+Blo) ----------
// A in LDS row-major bf16, row=point, col=k, pitch AROW. Wave covers ntiles [ntbase..ntbase+3].
template<int MT>
__device__ __forceinline__ void gemm_split(const unsigned short* Ahi, const unsigned short* Alo,
                                           const unsigned short* __restrict__ Bp,
                                           f32x4 acc[MT][4], int lane, int ntbase) {
#pragma unroll
    for (int mt = 0; mt < MT; mt++)
#pragma unroll
        for (int nt = 0; nt < 4; nt++) acc[mt][nt] = (f32x4){0.f, 0.f, 0.f, 0.f};
    const int r15 = lane & 15, q = lane >> 4;
    for (int kt = 0; kt < 8; kt++) {
        s16x8 bh[4], bl[4];
#pragma unroll
        for (int nt = 0; nt < 4; nt++) {
            const s16x8* bp = ((const s16x8*)Bp) + (size_t)((ntbase + nt) * 8 + kt) * 128 + lane;
            bh[nt] = bp[0];
            bl[nt] = bp[64];
        }
        const int kc = kt * 32 + q * 8;
#pragma unroll
        for (int mt = 0; mt < MT; mt++) {
            s16x8 ah = *(const s16x8*)(Ahi + (mt * 16 + r15) * AROW + kc);
            s16x8 al = *(const s16x8*)(Alo + (mt * 16 + r15) * AROW + kc);
#pragma unroll
            for (int nt = 0; nt < 4; nt++) {
                acc[mt][nt] = __builtin_amdgcn_mfma_f32_16x16x32_bf16(ah, bh[nt], acc[mt][nt], 0, 0, 0);
                acc[mt][nt] = __builtin_amdgcn_mfma_f32_16x16x32_bf16(ah, bl[nt], acc[mt][nt], 0, 0, 0);
                acc[mt][nt] = __builtin_amdgcn_mfma_f32_16x16x32_bf16(al, bh[nt], acc[mt][nt], 0, 0, 0);
                acc[mt][nt] = __builtin_amdgcn_mfma_f32_16x16x32_bf16(al, bl[nt], acc[mt][nt], 0, 0, 0);
            }
        }
    }
}

// dual (value + tangent) variant sharing B-fragment loads
template<int MT>
__device__ __forceinline__ void gemm_dual(const unsigned short* Avh, const unsigned short* Avl,
                                          const unsigned short* Ath, const unsigned short* Atl,
                                          const unsigned short* __restrict__ Bp,
                                          f32x4 av[MT][4], f32x4 at[MT][4], int lane, int ntbase) {
#pragma unroll
    for (int mt = 0; mt < MT; mt++)
#pragma unroll
        for (int nt = 0; nt < 4; nt++) {
            av[mt][nt] = (f32x4){0.f, 0.f, 0.f, 0.f};
            at[mt][nt] = (f32x4){0.f, 0.f, 0.f, 0.f};
        }
    const int r15 = lane & 15, q = lane >> 4;
    for (int kt = 0; kt < 8; kt++) {
        s16x8 bh[4], bl[4];
#pragma unroll
        for (int nt = 0; nt < 4; nt++) {
            const s16x8* bp = ((const s16x8*)Bp) + (size_t)((ntbase + nt) * 8 + kt) * 128 + lane;
            bh[nt] = bp[0];
            bl[nt] = bp[64];
        }
        const int kc = kt * 32 + q * 8;
#pragma unroll
        for (int mt = 0; mt < MT; mt++) {
            s16x8 avh = *(const s16x8*)(Avh + (mt * 16 + r15) * AROW + kc);
            s16x8 avl = *(const s16x8*)(Avl + (mt * 16 + r15) * AROW + kc);
            s16x8 ath = *(const s16x8*)(Ath + (mt * 16 + r15) * AROW + kc);
            s16x8 atl = *(const s16x8*)(Atl + (mt * 16 + r15) * AROW + kc);
#pragma unroll
            for (int nt = 0; nt < 4; nt++) {
                av[mt][nt] = __builtin_amdgcn_mfma_f32_16x16x32_bf16(avh, bh[nt], av[mt][nt], 0, 0, 0);
                av[mt][nt] = __builtin_amdgcn_mfma_f32_16x16x32_bf16(avh, bl[nt], av[mt][nt], 0, 0, 0);
                av[mt][nt] = __builtin_amdgcn_mfma_f32_16x16x32_bf16(avl, bh[nt], av[mt][nt], 0, 0, 0);
                av[mt][nt] = __builtin_amdgcn_mfma_f32_16x16x32_bf16(avl, bl[nt], av[mt][nt], 0, 0, 0);
                at[mt][nt] = __builtin_amdgcn_mfma_f32_16x16x32_bf16(ath, bh[nt], at[mt][nt], 0, 0, 0);
                at[mt][nt] = __builtin_amdgcn_mfma_f32_16x16x32_bf16(ath, bl[nt], at[mt][nt], 0, 0, 0);
                at[mt][nt] = __builtin_amdgcn_mfma_f32_16x16x32_bf16(atl, bh[nt], at[mt][nt], 0, 0, 0);
                at[mt][nt] = __builtin_amdgcn_mfma_f32_16x16x32_bf16(atl, bl[nt], at[mt][nt], 0, 0, 0);
            }
        }
    }
}

// epilogue: h = softplus(z + b), split to bf16 hi/lo, store into LDS A buffers.
// C/D layout: row = (lane>>4)*4 + reg, col = lane&15 (within tile).
template<int MT>
__device__ __forceinline__ void epi_hidden(f32x4 acc[MT][4], const float* __restrict__ b,
                                           unsigned short* Ahi, unsigned short* Alo,
                                           int lane, int wn0) {
    const int r15 = lane & 15, q = lane >> 4;
#pragma unroll
    for (int mt = 0; mt < MT; mt++)
#pragma unroll
        for (int nt = 0; nt < 4; nt++) {
            int col = wn0 + nt * 16 + r15;
            float bb = b[col];
#pragma unroll
            for (int reg = 0; reg < 4; reg++) {
                int row = mt * 16 + q * 4 + reg;
                float h = softplus_fast(acc[mt][nt][reg] + bb);
                unsigned short hi = f2bf(h);
                Ahi[row * AROW + col] = hi;
                Alo[row * AROW + col] = f2bf(h - bf2f(hi));
            }
        }
}

template<int MT>
__device__ __forceinline__ void epi_dual(f32x4 av[MT][4], f32x4 at[MT][4], const float* __restrict__ b,
                                         unsigned short* Avh, unsigned short* Avl,
                                         unsigned short* Ath, unsigned short* Atl,
                                         int lane, int wn0) {
    const int r15 = lane & 15, q = lane >> 4;
#pragma unroll
    for (int mt = 0; mt < MT; mt++)
#pragma unroll
        for (int nt = 0; nt < 4; nt++) {
            int col = wn0 + nt * 16 + r15;
            float bb = b[col];
#pragma unroll
            for (int reg = 0; reg < 4; reg++) {
                int row = mt * 16 + q * 4 + reg;
                float z = av[mt][nt][reg] + bb;
                float h = softplus_fast(z);
                float ht = sigmoid_fast(z) * at[mt][nt][reg];
                unsigned short hi = f2bf(h);
                Avh[row * AROW + col] = hi;
                Avl[row * AROW + col] = f2bf(h - bf2f(hi));
                hi = f2bf(ht);
                Ath[row * AROW + col] = hi;
                Atl[row * AROW + col] = f2bf(ht - bf2f(hi));
            }
        }
}

// layer3 activation + W4 dot, reduced across the 16 cols each quad owns.
template<int MT>
__device__ __forceinline__ void l4_reduce(f32x4 acc[MT][4], const float* __restrict__ b3,
                                          const float* __restrict__ W4,
                                          float* partial, int lane, int wn0) {
    const int r15 = lane & 15, q = lane >> 4;
    float w4v[4], b3v[4];
#pragma unroll
    for (int nt = 0; nt < 4; nt++) {
        int col = wn0 + nt * 16 + r15;
        w4v[nt] = W4[col]; b3v[nt] = b3[col];
    }
#pragma unroll
    for (int mt = 0; mt < MT; mt++)
#pragma unroll
        for (int reg = 0; reg < 4; reg++) {
            float p = 0.f;
#pragma unroll
            for (int nt = 0; nt < 4; nt++)
                p += softplus_fast(acc[mt][nt][reg] + b3v[nt]) * w4v[nt];
#pragma unroll
            for (int m = 1; m < 16; m <<= 1) p += __shfl_xor(p, m, 64);
            if (r15 == 0) partial[mt * 16 + q * 4 + reg] = p;
        }
}

template<int MT>
__device__ __forceinline__ void l4_reduce_dual(f32x4 av[MT][4], f32x4 at[MT][4],
                                               const float* __restrict__ b3, const float* __restrict__ W4,
                                               float* pv, float* pt, int lane, int wn0) {
    const int r15 = lane & 15, q = lane >> 4;
    float w4v[4], b3v[4];
#pragma unroll
    for (int nt = 0; nt < 4; nt++) {
        int col = wn0 + nt * 16 + r15;
        w4v[nt] = W4[col]; b3v[nt] = b3[col];
    }
#pragma unroll
    for (int mt = 0; mt < MT; mt++)
#pragma unroll
        for (int reg = 0; reg < 4; reg++) {
            float sv = 0.f, st = 0.f;
#pragma unroll
            for (int nt = 0; nt < 4; nt++) {
                float z = av[mt][nt][reg] + b3v[nt];
                sv += softplus_fast(z) * w4v[nt];
                st += sigmoid_fast(z) * at[mt][nt][reg] * w4v[nt];
            }
#pragma unroll
            for (int m = 1; m < 16; m <<= 1) {
                sv += __shfl_xor(sv, m, 64);
                st += __shfl_xor(st, m, 64);
            }
            if (r15 == 0) {
                pv[mt * 16 + q * 4 + reg] = sv;
                pt[mt * 16 + q * 4 + reg] = st;
            }
        }
}

// ---------------- coarse: block = (ray, half), 64 samples, M=64 per wave ----------------
__global__ __launch_bounds__(256, 2)
void coarse_mfma(const float* __restrict__ ray0, const float* __restrict__ rdg,
                 const float* __restrict__ W1, const float* __restrict__ b1,
                 const unsigned short* __restrict__ P2, const float* __restrict__ b2,
                 const unsigned short* __restrict__ P3, const float* __restrict__ b3,
                 const float* __restrict__ W4, const float* __restrict__ b4,
                 float* __restrict__ val_out, float* __restrict__ dprop_out) {
    __shared__ __align__(16) unsigned short Ahi[64 * AROW];
    __shared__ __align__(16) unsigned short Alo[64 * AROW];
    __shared__ float shp[9];
    __shared__ float partial[4][64];
    const int tid = threadIdx.x;
    const int lane = tid & 63, wave = tid >> 6;
    const int r = blockIdx.x >> 1, shalf = blockIdx.x & 1;

    if (tid == 0) {
        float o0 = ray0[3 * r], o1 = ray0[3 * r + 1], o2 = ray0[3 * r + 2];
        float v0 = rdg[3 * r], v1 = rdg[3 * r + 1], v2 = rdg[3 * r + 2];
        const float pd = 0.55f, lim = pd + 1e-6f;
        float di[6]; int insk[6]; int cnt = 0;
        for (int k = 0; k < 6; k++) {
            int a = k % 3;
            float pl = (k < 3) ? pd : -pd;
            float den = (a == 0) ? v0 : ((a == 1) ? v1 : v2);
            if (fabsf(den) < 1e-9f) den = 1e-9f;
            float oa = (a == 0) ? o0 : ((a == 1) ? o1 : o2);
            float dd = (pl - oa) / den;
            float px = o0 + dd * v0, py = o1 + dd * v1, pz = o2 + dd * v2;
            int ins = (fabsf(px) <= lim) && (fabsf(py) <= lim) && (fabsf(pz) <= lim);
            di[k] = dd; insk[k] = ins; cnt += ins;
        }
        float dn = 0.f, dfar = 0.f, maskc = 0.f;
        if (cnt == 2) {
            maskc = 1.f;
            int k1 = -1, k2 = -1;
            for (int k = 0; k < 6; k++) if (insk[k]) { if (k1 < 0) k1 = k; else k2 = k; }
            float nrd = sqrtf(v0 * v0 + v1 * v1 + v2 * v2);
            float ax = di[k1] * v0, ay = di[k1] * v1, az = di[k1] * v2;
            float d1n = sqrtf(ax * ax + ay * ay + az * az) / nrd;
            float bx = di[k2] * v0, by = di[k2] * v1, bz = di[k2] * v2;
            float d2n = sqrtf(bx * bx + by * by + bz * bz) / nrd;
            dn = fminf(d1n, d2n); dfar = fmaxf(d1n, d2n);
        }
        shp[0] = dn; shp[1] = dfar; shp[2] = maskc;
        shp[3] = o0; shp[4] = o1; shp[5] = o2;
        shp[6] = v0; shp[7] = v1; shp[8] = v2;
    }
    __syncthreads();
    // layer1 (fp32) + split store
    {
        const int pt = tid >> 2, jb = (tid & 3) << 6;
        const int s = shalf * 64 + pt;
        float t = (float)s * (1.0f / 127.0f);
        float d = (shp[2] != 0.f) ? (shp[0] + t * (shp[1] - shp[0])) : (t * 2.4f);
        if ((tid & 3) == 0) dprop_out[s * NRAY + r] = d;
        float px = shp[3] + d * shp[6], py = shp[4] + d * shp[7], pz = shp[5] + d * shp[8];
        for (int j = jb; j < jb + 64; j += 4) {
            float4 wa = *(const float4*)(W1 + j);
            float4 wb = *(const float4*)(W1 + 256 + j);
            float4 wc = *(const float4*)(W1 + 512 + j);
            float4 bb = *(const float4*)(b1 + j);
            float z[4];
            z[0] = fmaf(px, wa.x, fmaf(py, wb.x, fmaf(pz, wc.x, bb.x)));
            z[1] = fmaf(px, wa.y, fmaf(py, wb.y, fmaf(pz, wc.y, bb.y)));
            z[2] = fmaf(px, wa.z, fmaf(py, wb.z, fmaf(pz, wc.z, bb.z)));
            z[3] = fmaf(px, wa.w, fmaf(py, wb.w, fmaf(pz, wc.w, bb.w)));
#pragma unroll
            for (int i = 0; i < 4; i++) {
                float h = softplus_fast(z[i]);
                unsigned short hi = f2bf(h);
                Ahi[pt * AROW + j + i] = hi;
                Alo[pt * AROW + j + i] = f2bf(h - bf2f(hi));
            }
        }
    }
    __syncthreads();
    f32x4 acc[4][4];
    gemm_split<4>(Ahi, Alo, P2, acc, lane, wave * 4);
    __syncthreads();
    epi_hidden<4>(acc, b2, Ahi, Alo, lane, wave * 64);
    __syncthreads();
    gemm_split<4>(Ahi, Alo, P3, acc, lane, wave * 4);
    l4_reduce<4>(acc, b3, W4, &partial[wave][0], lane, wave * 64);
    __syncthreads();
    if (tid < 64) {
        float v = partial[0][tid] + partial[1][tid] + partial[2][tid] + partial[3][tid] + b4[0];
        val_out[(shalf * 64 + tid) * NRAY + r] = v;
    }
}

// ---------------- fp32 fixup of near-zero coarse vals (sign fidelity) ----------------
__global__ __launch_bounds__(64)
void fixup_kernel(float* __restrict__ val, const float* __restrict__ dprop,
                  const float* __restrict__ ray0, const float* __restrict__ rdg,
                  const float* __restrict__ W1, const float* __restrict__ b1,
                  const float* __restrict__ W2, const float* __restrict__ b2,
                  const float* __restrict__ W3, const float* __restrict__ b3,
                  const float* __restrict__ W4, const float* __restrict__ b4) {
    __shared__ float h1[HD];
    __shared__ float h2[HD];
    const int wid = blockIdx.x, lane = threadIdx.x;
    const int idx = wid * 64 + lane;
    float v = val[idx];
    unsigned long long m = __ballot(fabsf(v) < 1e-3f);
    const int c0 = lane * 4;
    while (m) {
        int bl = __ffsll((unsigned long long)m) - 1;
        m &= m - 1;
        int bidx = wid * 64 + bl;
        int rr = bidx & (NRAY - 1);
        float d = dprop[bidx];
        float px = ray0[3 * rr] + d * rdg[3 * rr];
        float py = ray0[3 * rr + 1] + d * rdg[3 * rr + 1];
        float pz = ray0[3 * rr + 2] + d * rdg[3 * rr + 2];
#pragma unroll
        for (int i = 0; i < 4; i++) {
            int j = c0 + i;
            float z = fmaf(px, W1[j], fmaf(py, W1[256 + j], fmaf(pz, W1[512 + j], b1[j])));
            h1[j] = softplus_precise(z);
        }
        __syncthreads();
        float4 a = make_float4(0.f, 0.f, 0.f, 0.f);
        for (int k = 0; k < HD; k++) {
            float hv = h1[k];
            float4 w = *(const float4*)(W2 + k * HD + c0);
            a.x = fmaf(hv, w.x, a.x); a.y = fmaf(hv, w.y, a.y);
            a.z = fmaf(hv, w.z, a.z); a.w = fmaf(hv, w.w, a.w);
        }
        h2[c0 + 0] = softplus_precise(a.x + b2[c0 + 0]);
        h2[c0 + 1] = softplus_precise(a.y + b2[c0 + 1]);
        h2[c0 + 2] = softplus_precise(a.z + b2[c0 + 2]);
        h2[c0 + 3] = softplus_precise(a.w + b2[c0 + 3]);
        __syncthreads();
        a = make_float4(0.f, 0.f, 0.f, 0.f);
        for (int k = 0; k < HD; k++) {
            float hv = h2[k];
            float4 w = *(const float4*)(W3 + k * HD + c0);
            a.x = fmaf(hv, w.x, a.x); a.y = fmaf(hv, w.y, a.y);
            a.z = fmaf(hv, w.z, a.z); a.w = fmaf(hv, w.w, a.w);
        }
        float p = softplus_precise(a.x + b3[c0 + 0]) * W4[c0 + 0]
                + softplus_precise(a.y + b3[c0 + 1]) * W4[c0 + 1]
                + softplus_precise(a.z + b3[c0 + 2]) * W4[c0 + 2]
                + softplus_precise(a.w + b3[c0 + 3]) * W4[c0 + 3];
#pragma unroll
        for (int s = 1; s < 64; s <<= 1) p += __shfl_xor(p, s, 64);
        if (lane == 0) val[bidx] = p + b4[0];
        __syncthreads();
    }
}

// ---------------- per-ray sign scan -> bracket + first secant ----------------
__global__ void scan_kernel(const float* __restrict__ val, const float* __restrict__ dprop,
                            float* __restrict__ dlow, float* __restrict__ flow,
                            float* __restrict__ dhigh, float* __restrict__ fhigh,
                            float* __restrict__ dpred, int* __restrict__ maskp) {
    int r = blockIdx.x * blockDim.x + threadIdx.x;
    if (r >= NRAY) return;
    float prev = val[r];
    int mask0 = prev < 0.f;
    float best = 3.4e38f; int bidx = 0;
    for (int s = 0; s < SSAMP - 1; s++) {
        float cur = val[(s + 1) * NRAY + r];
        float pr = prev * cur;
        float sg = (pr > 0.f) ? 1.f : ((pr < 0.f) ? -1.f : 0.f);
        float cost = sg * (float)(SSAMP - s);
        if (cost < best) { best = cost; bidx = s; }
        prev = cur;
    }
    if (1.0f < best) { best = 1.0f; bidx = SSAMP - 1; }
    float f_low = val[bidx * NRAY + r];
    int idxh = min(bidx + 1, SSAMP - 1);
    float d_low = dprop[bidx * NRAY + r];
    float d_high = dprop[idxh * NRAY + r];
    float f_high = val[idxh * NRAY + r];
    int mk = (best < 0.f) && (f_low < 0.f) && mask0;
    float den = f_high - f_low;
    if (fabsf(den) < 1e-12f) den = 1e-12f;
    float dp = -f_low * (d_high - d_low) / den + d_low;
    dlow[r] = d_low; flow[r] = f_low; dhigh[r] = d_high; fhigh[r] = f_high;
    dpred[r] = dp; maskp[r] = mk;
}

// ---------------- fused 8-iteration secant (block = 64 rays) ----------------
__global__ __launch_bounds__(256, 2)
void secant_mfma(const float* __restrict__ ray0, const float* __restrict__ rdg,
                 const float* __restrict__ W1, const float* __restrict__ b1,
                 const unsigned short* __restrict__ P2, const float* __restrict__ b2,
                 const unsigned short* __restrict__ P3, const float* __restrict__ b3,
                 const float* __restrict__ W4, const float* __restrict__ b4,
                 const float* __restrict__ dlow, const float* __restrict__ flow,
                 const float* __restrict__ dhigh, const float* __restrict__ fhigh,
                 float* __restrict__ dpred) {
    __shared__ __align__(16) unsigned short Ahi[64 * AROW];
    __shared__ __align__(16) unsigned short Alo[64 * AROW];
    __shared__ float partial[4][64];
    __shared__ float dl[64], fl[64], dh[64], fh[64], dp[64];
    const int tid = threadIdx.x;
    const int lane = tid & 63, wave = tid >> 6;
    const int r0 = blockIdx.x * 64;
    if (tid < 64) {
        dl[tid] = dlow[r0 + tid]; fl[tid] = flow[r0 + tid];
        dh[tid] = dhigh[r0 + tid]; fh[tid] = fhigh[r0 + tid];
        dp[tid] = dpred[r0 + tid];
    }
    __syncthreads();
    for (int it = 0; it < 8; it++) {
        {
            const int pt = tid >> 2, jb = (tid & 3) << 6;
            const int rr = r0 + pt;
            float d = dp[pt];
            float px = ray0[3 * rr] + d * rdg[3 * rr];
            float py = ray0[3 * rr + 1] + d * rdg[3 * rr + 1];
            float pz = ray0[3 * rr + 2] + d * rdg[3 * rr + 2];
            for (int j = jb; j < jb + 64; j += 4) {
                float4 wa = *(const float4*)(W1 + j);
                float4 wb = *(const float4*)(W1 + 256 + j);
                float4 wc = *(const float4*)(W1 + 512 + j);
                float4 bb = *(const float4*)(b1 + j);
                float z[4];
                z[0] = fmaf(px, wa.x, fmaf(py, wb.x, fmaf(pz, wc.x, bb.x)));
                z[1] = fmaf(px, wa.y, fmaf(py, wb.y, fmaf(pz, wc.y, bb.y)));
                z[2] = fmaf(px, wa.z, fmaf(py, wb.z, fmaf(pz, wc.z, bb.z)));
                z[3] = fmaf(px, wa.w, fmaf(py, wb.w, fmaf(pz, wc.w, bb.w)));
#pragma unroll
                for (int i = 0; i < 4; i++) {
                    float h = softplus_fast(z[i]);
                    unsigned short hi = f2bf(h);
                    Ahi[pt * AROW + j + i] = hi;
                    Alo[pt * AROW + j + i] = f2bf(h - bf2f(hi));
                }
            }
        }
        __syncthreads();
        f32x4 acc[4][4];
        gemm_split<4>(Ahi, Alo, P2, acc, lane, wave * 4);
        __syncthreads();
        epi_hidden<4>(acc, b2, Ahi, Alo, lane, wave * 64);
        __syncthreads();
        gemm_split<4>(Ahi, Alo, P3, acc, lane, wave * 4);
        l4_reduce<4>(acc, b3, W4, &partial[wave][0], lane, wave * 64);
        __syncthreads();
        if (tid < 64) {
            float fm = partial[0][tid] + partial[1][tid] + partial[2][tid] + partial[3][tid] + b4[0];
            float dpv = dp[tid];
            float dlv = dl[tid], flv = fl[tid], dhv = dh[tid], fhv = fh[tid];
            if (fm < 0.f) { dlv = dpv; flv = fm; } else { dhv = dpv; fhv = fm; }
            float den = fhv - flv;
            if (fabsf(den) < 1e-12f) den = 1e-12f;
            dp[tid] = -flv * (dhv - dlv) / den + dlv;
            dl[tid] = dlv; fl[tid] = flv; dh[tid] = dhv; fh[tid] = fhv;
        }
        __syncthreads();
    }
    if (tid < 64) dpred[r0 + tid] = dp[tid];
}

// ---------------- final dual-number eval + implicit correction (block = 32 rays) ----------------
__global__ __launch_bounds__(256, 2)
void final_mfma(const float* __restrict__ ray0, const float* __restrict__ rdg,
                const float* __restrict__ W1, const float* __restrict__ b1,
                const unsigned short* __restrict__ P2, const float* __restrict__ b2,
                const unsigned short* __restrict__ P3, const float* __restrict__ b3,
                const float* __restrict__ W4, const float* __restrict__ b4,
                const float* __restrict__ dpred, const int* __restrict__ maskp,
                float* __restrict__ out) {
    __shared__ __align__(16) unsigned short Avh[32 * AROW];
    __shared__ __align__(16) unsigned short Avl[32 * AROW];
    __shared__ __align__(16) unsigned short Ath[32 * AROW];
    __shared__ __align__(16) unsigned short Atl[32 * AROW];
    __shared__ float pv[4][32], pt_[4][32];
    const int tid = threadIdx.x;
    const int lane = tid & 63, wave = tid >> 6;
    const int r0 = blockIdx.x * 32;
    {
        const int pt = tid >> 3, jb = (tid & 7) << 5;
        const int rr = r0 + pt;
        float d = dpred[rr];
        float v0 = rdg[3 * rr], v1 = rdg[3 * rr + 1], v2 = rdg[3 * rr + 2];
        float px = ray0[3 * rr] + d * v0;
        float py = ray0[3 * rr + 1] + d * v1;
        float pz = ray0[3 * rr + 2] + d * v2;
        for (int j = jb; j < jb + 32; j += 4) {
            float4 wa = *(const float4*)(W1 + j);
            float4 wb = *(const float4*)(W1 + 256 + j);
            float4 wc = *(const float4*)(W1 + 512 + j);
            float4 bb = *(const float4*)(b1 + j);
            float z[4], zt[4];
            z[0] = fmaf(px, wa.x, fmaf(py, wb.x, fmaf(pz, wc.x, bb.x)));
            z[1] = fmaf(px, wa.y, fmaf(py, wb.y, fmaf(pz, wc.y, bb.y)));
            z[2] = fmaf(px, wa.z, fmaf(py, wb.z, fmaf(pz, wc.z, bb.z)));
            z[3] = fmaf(px, wa.w, fmaf(py, wb.w, fmaf(pz, wc.w, bb.w)));
            zt[0] = fmaf(v0, wa.x, fmaf(v1, wb.x, v2 * wc.x));
            zt[1] = fmaf(v0, wa.y, fmaf(v1, wb.y, v2 * wc.y));
            zt[2] = fmaf(v0, wa.z, fmaf(v1, wb.z, v2 * wc.z));
            zt[3] = fmaf(v0, wa.w, fmaf(v1, wb.w, v2 * wc.w));
#pragma unroll
            for (int i = 0; i < 4; i++) {
                float h = softplus_fast(z[i]);
                float ht = sigmoid_fast(z[i]) * zt[i];
                unsigned short hi = f2bf(h);
                Avh[pt * AROW + j + i] = hi;
                Avl[pt * AROW + j + i] = f2bf(h - bf2f(hi));
                hi = f2bf(ht);
                Ath[pt * AROW + j + i] = hi;
                Atl[pt * AROW + j + i] = f2bf(ht - bf2f(hi));
            }
        }
    }
    __syncthreads();
    f32x4 av[2][4], at[2][4];
    gemm_dual<2>(Avh, Avl, Ath, Atl, P2, av, at, lane, wave * 4);
    __syncthreads();
    epi_dual<2>(av, at, b2, Avh, Avl, Ath, Atl, lane, wave * 64);
    __syncthreads();
    gemm_dual<2>(Avh, Avl, Ath, Atl, P3, av, at, lane, wave * 4);
    l4_reduce_dual<2>(av, at, b3, W4, &pv[wave][0], &pt_[wave][0], lane, wave * 64);
    __syncthreads();
    if (tid < 32) {
        int rr = r0 + tid;
        float f = pv[0][tid] + pv[1][tid] + pv[2][tid] + pv[3][tid] + b4[0];
        float ft = pt_[0][tid] + pt_[1][tid] + pt_[2][tid] + pt_[3][tid];
        if (fabsf(ft) < 1e-6f) ft = (ft < 0.f) ? -1e-6f : 1e-6f;
        float dres = dpred[rr] - f / ft;
        out[rr] = maskp[rr] ? dres : 0.0f;
    }
}

extern "C" void kernel_launch(void* const* d_in, const int* in_sizes, int n_in,
                              void* d_out, int out_size, void* d_ws, size_t ws_size,
                              hipStream_t stream) {
    const float* ray0 = (const float*)d_in[0];
    const float* rdg  = (const float*)d_in[1];
    const float* W1 = (const float*)d_in[2];
    const float* b1 = (const float*)d_in[3];
    const float* W2 = (const float*)d_in[4];
    const float* b2 = (const float*)d_in[5];
    const float* W3 = (const float*)d_in[6];
    const float* b3 = (const float*)d_in[7];
    const float* W4 = (const float*)d_in[8];
    const float* b4 = (const float*)d_in[9];
    float* out = (float*)d_out;

    float* ws = (float*)d_ws;
    float* val    = ws;                                 // 1048576 (s-major [s][r])
    float* dprop  = ws + (size_t)SSAMP * NRAY;          // 1048576
    float* s_dlow  = ws + (size_t)2 * SSAMP * NRAY;
    float* s_flow  = s_dlow + NRAY;
    float* s_dhigh = s_flow + NRAY;
    float* s_fhigh = s_dhigh + NRAY;
    float* s_dpred = s_fhigh + NRAY;
    int*   s_mask  = (int*)(s_dpred + NRAY);
    unsigned short* P2 = (unsigned short*)(s_dpred + 2 * NRAY);  // 131072 shorts (hi+lo)
    unsigned short* P3 = P2 + 131072;

    hipLaunchKernelGGL(pack_kernel, dim3(256), dim3(256), 0, stream, W2, W3, P2, P3);
    hipLaunchKernelGGL(coarse_mfma, dim3(NRAY * 2), dim3(256), 0, stream,
                       ray0, rdg, W1, b1, P2, b2, P3, b3, W4, b4, val, dprop);
    hipLaunchKernelGGL(fixup_kernel, dim3(SSAMP * NRAY / 64), dim3(64), 0, stream,
                       val, dprop, ray0, rdg, W1, b1, W2, b2, W3, b3, W4, b4);
    hipLaunchKernelGGL(scan_kernel, dim3(NRAY / 256), dim3(256), 0, stream,
                       val, dprop, s_dlow, s_flow, s_dhigh, s_fhigh, s_dpred, s_mask);
    hipLaunchKernelGGL(secant_mfma, dim3(NRAY / 64), dim3(256), 0, stream,
                       ray0, rdg, W1, b1, P2, b2, P3, b3, W4, b4,
                       s_dlow, s_flow, s_dhigh, s_fhigh, s_dpred);
    hipLaunchKernelGGL(final_mfma, dim3(NRAY / 32), dim3(256), 0, stream,
                       ray0, rdg, W1, b1, P2, b2, P3, b3, W4, b4,
                       s_dpred, s_mask, out);
}